// Round 10
// baseline (80.489 us; speedup 1.0000x reference)
//
#include <hip/hip_runtime.h>

// Ball query, fully fused, sort-free: ONE kernel, ZERO cross-block deps,
// ZERO LDS atomics, ONE barrier. B=4, N1=2048, N2=8192, K=64, r=0.1.
//
// Design (R9 post-mortem): hit extraction works from a 128-bit-per-lane
// register bitmap keyed by ORIGINAL key index — so keys never need to be
// reordered, only *identified*. Each block (1024 thr = 16 waves, 1/CU):
//
//  BUILD (one pass, ballot-based, no atomics):
//    - keys stored at original index in LDS SoA kx/ky/kz (96 KB)
//    - per-(x,y)-column candidate bitmaps colbm[25][130] u64 (26 KB):
//      wave owning 64-key word w computes, for column c=(cx,cy),
//      word = ballot(keycx==cx) & ballot(keycy==cy) — 10 ballots/round,
//      lanes 0..24 each write one column's word.
//  QUERY (2 per wave):
//    - octant = <=4 (x,y) columns (cell 0.2 = 2r)
//    - lane L owns key range [128L,128L+128) = words 2L,2L+1 of every
//      column bitmap; reads them (b128), tests candidates via LDS gathers,
//      ORs hits into two u64 REGISTERS
//    - extraction (verified R3-R9): popcount + wave prefix -> ordered emit
//      of first K set bits, pad with first-hit index (0 if none).

constexpr int   K    = 64;
constexpr float R2   = 0.01f;   // 0.1^2
constexpr int   B    = 4;
constexpr int   N1   = 2048;
constexpr int   N2   = 8192;
constexpr int   GC   = 5;                  // grid cells per dim
constexpr float INVCELL = 5.0f;            // 1 / 0.2
constexpr int   NCOL    = GC * GC;         // 25 (x,y) columns
constexpr int   NWORD   = N2 / 64;         // 128 bitmap words per column
constexpr int   WSTRIDE = NWORD + 2;       // 130: even (16B-align pairs) + bank spread
constexpr int   BLOCKS  = 256;             // 1 per CU
constexpr int   THREADS = 1024;            // 16 waves
constexpr int   WAVES   = 16;
constexpr int   QPB     = (B * N1) / BLOCKS;   // 32 queries/block
constexpr int   QPW     = QPB / WAVES;         // 2 queries/wave

__device__ __forceinline__ int cell_of(float v) {
    int c = (int)(v * INVCELL);
    return c < 0 ? 0 : (c > GC - 1 ? GC - 1 : c);
}

// 5-way select of wave-uniform values by lane-varying s (cndmask chain, no scratch)
__device__ __forceinline__ unsigned long long sel5(
    unsigned long long a0, unsigned long long a1, unsigned long long a2,
    unsigned long long a3, unsigned long long a4, int s)
{
    unsigned long long r = a0;
    r = (s == 1) ? a1 : r;
    r = (s == 2) ? a2 : r;
    r = (s == 3) ? a3 : r;
    r = (s == 4) ? a4 : r;
    return r;
}

__global__ __launch_bounds__(1024) void ballquery_fused2_kernel(
    const float* __restrict__ query,   // [B*N1, 3]
    const float* __restrict__ key,     // [B*N2, 3]
    int* __restrict__ out)             // [B*N1, K]
{
    __shared__ float kx[N2], ky[N2], kz[N2];                 // 96 KB, orig order
    __shared__ unsigned long long colbm[NCOL * WSTRIDE];     // 26 KB

    const int blk  = blockIdx.x;
    const int b    = blk >> 6;                // 64 blocks per batch
    const int t    = threadIdx.x;
    const int lane = t & 63;
    const int wv   = t >> 6;

    // ---------------- BUILD: ballot bitmaps, no atomics ----------------
    const float* kb = key + (size_t)b * N2 * 3;
    const int cdiv = lane / 5;                // for lane<25: column (cx,cy)
    const int cmod = lane - cdiv * 5;

    #pragma unroll
    for (int r = 0; r < NWORD / WAVES; ++r) { // 8 rounds, each wave owns a word
        const int word = r * WAVES + wv;      // 0..127
        const int i = (word << 6) + lane;     // coalesced key index
        const float x = kb[i * 3 + 0];
        const float y = kb[i * 3 + 1];
        const float z = kb[i * 3 + 2];
        kx[i] = x; ky[i] = y; kz[i] = z;      // stride-1 LDS stores

        const int cx = cell_of(x);
        const int cy = cell_of(y);
        const unsigned long long bx0 = __ballot(cx == 0);
        const unsigned long long bx1 = __ballot(cx == 1);
        const unsigned long long bx2 = __ballot(cx == 2);
        const unsigned long long bx3 = __ballot(cx == 3);
        const unsigned long long bx4 = __ballot(cx == 4);
        const unsigned long long by0 = __ballot(cy == 0);
        const unsigned long long by1 = __ballot(cy == 1);
        const unsigned long long by2 = __ballot(cy == 2);
        const unsigned long long by3 = __ballot(cy == 3);
        const unsigned long long by4 = __ballot(cy == 4);

        if (lane < NCOL) {                    // lane c writes column c's word
            const unsigned long long m =
                sel5(bx0, bx1, bx2, bx3, bx4, cdiv) &
                sel5(by0, by1, by2, by3, by4, cmod);
            colbm[lane * WSTRIDE + word] = m;
        }
    }
    __syncthreads();                          // the ONLY barrier

    // ---------------- QUERY: 2 per wave, hits in registers ----------------
    const int qbase = blk * QPB + wv * QPW;

    for (int qi = 0; qi < QPW; ++qi) {
        const int q = qbase + qi;

        const float qx = query[q * 3 + 0];    // q wave-uniform -> s_load
        const float qy = query[q * 3 + 1];
        const float qz = query[q * 3 + 2];

        // Octant columns the ball can touch (cell = 2r: +/-1 on near side).
        const float ux = qx * INVCELL, uy = qy * INVCELL;
        const int cx = cell_of(qx), cy = cell_of(qy);
        const int nx = (ux - cx < 0.5f) ? cx - 1 : cx + 1;
        const int ny = (uy - cy < 0.5f) ? cy - 1 : cy + 1;
        const int xlo = max(0, min(cx, nx)), xhi = min(GC - 1, max(cx, nx));
        const int ylo = max(0, min(cy, ny)), yhi = min(GC - 1, max(cy, ny));

        // Lane owns key range [128*lane, 128*lane+128) = words w0, w0+1.
        const int w0 = lane << 1;
        const int ibase = lane << 7;
        unsigned long long hit0 = 0ull, hit1 = 0ull;

        for (int xx = xlo; xx <= xhi; ++xx) {
            for (int yy = ylo; yy <= yhi; ++yy) {
                const int c = xx * GC + yy;
                const unsigned long long cand0 = colbm[c * WSTRIDE + w0];
                const unsigned long long cand1 = colbm[c * WSTRIDE + w0 + 1];

                unsigned long long m = cand0;
                while (m) {
                    const int bp = __builtin_ctzll(m);
                    m &= m - 1;
                    const int i = ibase + bp;
                    const float dx = kx[i] - qx;
                    const float dy = ky[i] - qy;
                    const float dz = kz[i] - qz;
                    if (dx * dx + dy * dy + dz * dz < R2)
                        hit0 |= 1ull << bp;
                }
                m = cand1;
                while (m) {
                    const int bp = __builtin_ctzll(m);
                    m &= m - 1;
                    const int i = ibase + 64 + bp;
                    const float dx = kx[i] - qx;
                    const float dy = ky[i] - qy;
                    const float dz = kz[i] - qz;
                    if (dx * dx + dy * dy + dz * dz < R2)
                        hit1 |= 1ull << bp;
                }
            }
        }

        // ---- extraction (verified logic; hit words already in registers)
        const int c0 = __popcll(hit0) + __popcll(hit1);

        int x = c0;                           // inclusive wave prefix sum
        #pragma unroll
        for (int off = 1; off < 64; off <<= 1) {
            int y = __shfl_up(x, off);
            if (lane >= off) x += y;
        }
        const int base = x - c0;
        const int cnt  = __shfl(x, 63);

        int fs;                               // lane's first set bit
        if      (hit0) fs = __builtin_ctzll(hit0);
        else if (hit1) fs = 64 + __builtin_ctzll(hit1);
        else           fs = 0;
        int myfirst = c0 ? ibase + fs : 0x7fffffff;
        #pragma unroll
        for (int off = 32; off; off >>= 1)
            myfirst = min(myfirst, __shfl_xor(myfirst, off));
        const int firstIdx = (cnt == 0) ? 0 : myfirst;

        int* op = out + q * K;                // emit set bits in key order
        int slot = base;
        unsigned long long m = hit0;
        while (m) {
            const int bp = __builtin_ctzll(m);
            m &= m - 1;
            if (slot < K) op[slot] = ibase + bp;
            ++slot;
        }
        m = hit1;
        while (m) {
            const int bp = __builtin_ctzll(m);
            m &= m - 1;
            if (slot < K) op[slot] = ibase + 64 + bp;
            ++slot;
        }

        const int kpad = cnt < K ? cnt : K;   // pad with firstIdx
        const int s2 = kpad + lane;
        if (s2 < K) op[s2] = firstIdx;
    }
}

extern "C" void kernel_launch(void* const* d_in, const int* in_sizes, int n_in,
                              void* d_out, int out_size, void* d_ws, size_t ws_size,
                              hipStream_t stream) {
    const float* query = (const float*)d_in[0];   // B*N1*3 floats
    const float* key   = (const float*)d_in[1];   // B*N2*3 floats
    int* out = (int*)d_out;                       // B*N1*K int32

    ballquery_fused2_kernel<<<BLOCKS, THREADS, 0, stream>>>(query, key, out);
}